// Round 12
// baseline (253.944 us; speedup 1.0000x reference)
//
#include <hip/hip_runtime.h>

#define BB 8
#define CC 64
#define NN 4096
#define JCH 8            // j-chunks in stats pass
#define LOG2E 1.4426950408889634f

typedef float f32x4  __attribute__((ext_vector_type(4)));
typedef float f32x16 __attribute__((ext_vector_type(16)));
typedef _Float16 half8_t __attribute__((ext_vector_type(8)));
typedef int int4v __attribute__((ext_vector_type(4)));
typedef unsigned uint2v __attribute__((ext_vector_type(2)));

// 32x32x16 f16 MFMA layouts (gfx950):
//   A[m][k]: m = lane&31, k = (lane>>5)*8 + idx   (8 halves)
//   B[k][n]: n = lane&31, k = (lane>>5)*8 + idx
//   C/D:     col = lane&31, row = (reg&3) + 8*(reg>>2) + 4*(lane>>5)
//
// SESSION LEDGER:
//   attn pinned ~57us across 8 structural variants (2 waves/SIMD grid-capped,
//   VALU 52% + MFMA 23% on separate pipes, no pipe saturable).
//   stats launch_bounds: (256,4) ONLY non-spilling config (R9/R10: 8 and 6
//   both cliff to 32-40 VGPR + 400-490MB scratch on the unified RF).
//   Budget audit (R11): kernels ~115us vs 169 wall -> ~50us is launch gaps.
//   R12: fuse combine into attn (last-ic-block finisher, device-scope
//   atomic + fences per G16). Launches 4 -> 3.

// ---------------------------------------------------------------------------
// Kernel A: fused 1x1-conv QKV via MFMA. grid (NN/32, B), block 384 (6 waves).
// ---------------------------------------------------------------------------
__global__ __launch_bounds__(384, 6) void qkv_kernel(
    const float* __restrict__ x,
    const float* __restrict__ Wf, const float* __restrict__ bf,
    const float* __restrict__ Wg, const float* __restrict__ bg,
    const float* __restrict__ Wh, const float* __restrict__ bh,
    _Float16* __restrict__ fT, _Float16* __restrict__ gT,
    _Float16* __restrict__ hT)
{
    __shared__ float xbuf[64][36];         // 9.2 KB, stride 36 floats

    const int tid  = threadIdx.x;
    const int lane = tid & 63;
    const int wv   = tid >> 6;             // 0..5
    const int l31  = lane & 31;
    const int q5   = lane >> 5;
    const int z    = wv >> 1;              // 0=f 1=g 2=h
    const int ot   = wv & 1;               // o-tile
    const int n0   = blockIdx.x * 32;
    const int b    = blockIdx.y;

    if (tid < 256) {
        const int row = tid >> 2;
        const int px4 = (tid & 3) * 8;
        const float* src = x + (size_t)(b * CC + row) * NN + n0 + px4;
        *(f32x4*)&xbuf[row][px4]     = *(const f32x4*)(src);
        *(f32x4*)&xbuf[row][px4 + 4] = *(const f32x4*)(src + 4);
    }
    __syncthreads();

    half8_t xf[4];
#pragma unroll
    for (int kc = 0; kc < 4; ++kc) {
        const int kb = kc * 16 + q5 * 8;
        int4v p;
#pragma unroll
        for (int h2 = 0; h2 < 4; ++h2) {
            p[h2] = __builtin_bit_cast(int, __builtin_amdgcn_cvt_pkrtz(
                xbuf[kb + h2 * 2][l31], xbuf[kb + h2 * 2 + 1][l31]));
        }
        xf[kc] = __builtin_bit_cast(half8_t, p);
    }

    const float* W    = (z == 0) ? Wf : ((z == 1) ? Wg : Wh);
    const float* bias = (z == 0) ? bf : ((z == 1) ? bg : bh);

    half8_t wf[4];
    {
        const float* wrow = W + (size_t)(ot * 32 + l31) * CC;
#pragma unroll
        for (int kc = 0; kc < 4; ++kc) {
            const f32x4 w0 = *(const f32x4*)(wrow + kc * 16 + q5 * 8);
            const f32x4 w1 = *(const f32x4*)(wrow + kc * 16 + q5 * 8 + 4);
            int4v p;
            p[0] = __builtin_bit_cast(int, __builtin_amdgcn_cvt_pkrtz(w0[0], w0[1]));
            p[1] = __builtin_bit_cast(int, __builtin_amdgcn_cvt_pkrtz(w0[2], w0[3]));
            p[2] = __builtin_bit_cast(int, __builtin_amdgcn_cvt_pkrtz(w1[0], w1[1]));
            p[3] = __builtin_bit_cast(int, __builtin_amdgcn_cvt_pkrtz(w1[2], w1[3]));
            wf[kc] = __builtin_bit_cast(half8_t, p);
        }
    }

    if (z < 2) {
        f32x16 acc = {};
#pragma unroll
        for (int kc = 0; kc < 4; ++kc)
            acc = __builtin_amdgcn_mfma_f32_32x32x16_f16(xf[kc], wf[kc], acc, 0, 0, 0);
        _Float16* dstT = (z == 0) ? fT : gT;
        const float scale = (z == 0) ? LOG2E : 1.0f;
        const float bv = bias[ot * 32 + l31];
#pragma unroll
        for (int r = 0; r < 16; ++r) {
            const int prow = (r & 3) + 8 * (r >> 2) + 4 * q5;
            dstT[(size_t)(b * NN + n0 + prow) * CC + ot * 32 + l31] =
                (_Float16)((acc[r] + bv) * scale);
        }
    } else {
        f32x16 acc = {};
#pragma unroll
        for (int kc = 0; kc < 4; ++kc)
            acc = __builtin_amdgcn_mfma_f32_32x32x16_f16(wf[kc], xf[kc], acc, 0, 0, 0);
        _Float16* hbase = hT + ((size_t)(b * (NN / 32) + blockIdx.x) * CC) * 32;
#pragma unroll
        for (int rb = 0; rb < 4; ++rb) {
            const f32x4 b4 = *(const f32x4*)(bias + ot * 32 + rb * 8 + q5 * 4);
#pragma unroll
            for (int k = 0; k < 4; ++k) {
                const int c = ot * 32 + rb * 8 + q5 * 4 + k;
                hbase[(size_t)c * 32 + l31] = (_Float16)(acc[rb * 4 + k] + b4[k]);
            }
        }
    }
}

// ---------------------------------------------------------------------------
// Kernel B: partial row sums of exp2(logits). grid (NN/128, B, JCH), block 256.
// launch_bounds (256,4): the ONLY verified non-spilling config (R9/R10).
// ---------------------------------------------------------------------------
__global__ __launch_bounds__(256, 4) void stats_kernel(
    const _Float16* __restrict__ fT, const _Float16* __restrict__ gT,
    float* __restrict__ lpart)
{
    __shared__ _Float16 gbuf[2][64][72];   // stride 72 halves

    const int lane = threadIdx.x & 63;
    const int wv   = threadIdx.x >> 6;
    const int b    = blockIdx.y;
    const int jc   = blockIdx.z;
    const int i0   = blockIdx.x * 128 + wv * 32;
    const int l31  = lane & 31;
    const int q5   = lane >> 5;

    half8_t a[4];
    const _Float16* fa = fT + (size_t)(b * NN + i0 + l31) * CC + q5 * 8;
#pragma unroll
    for (int kc = 0; kc < 4; ++kc) a[kc] = *(const half8_t*)(fa + kc * 16);

    const _Float16* gchunk = gT + (size_t)(b * NN + jc * (NN / JCH)) * CC;
    const int T = NN / JCH / 64;   // 8 tiles of 64 j

    const int srow = wv * 16 + (lane >> 3);
    const int scol = (lane & 7) * 8;

    {   // stage tile 0
        const half8_t v0 = *(const half8_t*)(gchunk + (size_t)srow * CC + scol);
        const half8_t v1 = *(const half8_t*)(gchunk + (size_t)(srow + 8) * CC + scol);
        *(half8_t*)&gbuf[0][srow][scol] = v0;
        *(half8_t*)&gbuf[0][srow + 8][scol] = v1;
    }
    __syncthreads();

    float l16[16];
#pragma unroll
    for (int r = 0; r < 16; ++r) l16[r] = 0.f;

    for (int t = 0; t < T; ++t) {
        const int buf = t & 1;
        const bool pf = (t + 1 < T);
        half8_t p0, p1;
        if (pf) {
            const _Float16* src = gchunk + (size_t)((t + 1) * 64 + srow) * CC + scol;
            p0 = *(const half8_t*)(src);
            p1 = *(const half8_t*)(src + 8 * CC);
        }
#pragma unroll
        for (int js = 0; js < 2; ++js) {
            const _Float16* grow = &gbuf[buf][js * 32 + l31][0] + q5 * 8;
            f32x16 s = {};
#pragma unroll
            for (int kc = 0; kc < 4; ++kc) {
                const half8_t bfr = *(const half8_t*)(grow + kc * 16);
                s = __builtin_amdgcn_mfma_f32_32x32x16_f16(a[kc], bfr, s, 0, 0, 0);
            }
#pragma unroll
            for (int r = 0; r < 16; ++r) l16[r] += __builtin_exp2f(s[r]);
        }
        if (pf) {
            *(half8_t*)&gbuf[buf ^ 1][srow][scol] = p0;
            *(half8_t*)&gbuf[buf ^ 1][srow + 8][scol] = p1;
        }
        __syncthreads();
    }

#pragma unroll
    for (int r = 0; r < 16; ++r) {
#pragma unroll
        for (int off = 1; off < 32; off <<= 1)
            l16[r] += __shfl_xor(l16[r], off);
    }

    if (l31 == 0) {
        float* lp = lpart + (size_t)jc * BB * NN + b * NN + i0;
#pragma unroll
        for (int rb = 0; rb < 4; ++rb) {
            f32x4 v;
#pragma unroll
            for (int k = 0; k < 4; ++k) v[k] = l16[rb * 4 + k];
            *(f32x4*)(lp + rb * 8 + q5 * 4) = v;
        }
    }
}

// ---------------------------------------------------------------------------
// Kernel C: partial out chunks + FUSED COMBINE. grid (NN/256, B, NICT=4).
// R8 compute structure (2-deep staging, 8 barriers, setprio, permlane dance,
// attn pinned 57.5us). NEW (R12): after pout writes, each block does a
// device-scope ACQ_REL fetch_add on cnt[b*16+jbx]; the LAST of the NICT
// ic-blocks for this (b, j-slice) re-reads the NICT pout chunks (same icc
// order as the old combine_kernel -> bit-identical sums), applies
// gamma*sum + x, writes out. Kills the combine launch + its gap; finisher
// work overlaps still-running attn blocks.
// ---------------------------------------------------------------------------
template <int NICT>
__global__ __launch_bounds__(256, 2) void attn_kernel(
    const _Float16* __restrict__ fT, const _Float16* __restrict__ gT,
    const _Float16* __restrict__ hT, const float* __restrict__ lpart,
    _Float16* __restrict__ pout,
    const float* __restrict__ xres, const float* __restrict__ gammap,
    float* __restrict__ outp, unsigned* __restrict__ cnt)
{
    constexpr int ichunk = NN / NICT;      // 1024
    __shared__ _Float16 fbuf[2][2][64][72];   // 36.9 KB
    __shared__ _Float16 hbuf[2][2][64][72];   // 36.9 KB
    __shared__ float nbbuf[ichunk];           // 4 KB
    __shared__ unsigned done_cnt;

    const int lane = threadIdx.x & 63;
    const int wv   = threadIdx.x >> 6;
    const int b    = blockIdx.y;
    const int ic   = blockIdx.z;
    const int l31  = lane & 31;
    const int q5   = lane >> 5;
    const int jbase = blockIdx.x * 256 + wv * 64;

    const int ibase  = ic * ichunk;
    const int tid    = threadIdx.x;

    // ---- fused rmerge: nbias for this i-chunk (identical jc-sum order) ----
    if (tid * 4 < ichunk) {
        const float* lp0 = lpart + b * NN + ibase + tid * 4;
        f32x4 sum = *(const f32x4*)(lp0);
#pragma unroll
        for (int jc = 1; jc < JCH; ++jc) {
            const f32x4 v = *(const f32x4*)(lp0 + (size_t)jc * BB * NN);
#pragma unroll
            for (int k = 0; k < 4; ++k) sum[k] += v[k];
        }
        f32x4 nb4;
#pragma unroll
        for (int k = 0; k < 4; ++k) nb4[k] = -__builtin_log2f(sum[k]);
        *(f32x4*)&nbbuf[tid * 4] = nb4;
    }

    half8_t bg[2][4];
#pragma unroll
    for (int jt = 0; jt < 2; ++jt) {
        const _Float16* grow = gT + (size_t)(b * NN + jbase + jt * 32 + l31) * CC + q5 * 8;
#pragma unroll
        for (int kc = 0; kc < 4; ++kc) bg[jt][kc] = *(const half8_t*)(grow + kc * 16);
    }

    f32x16 acc[2][2] = {};   // [jt][ct]

    const _Float16* fchunk = fT + ((size_t)b * NN + ibase) * CC;
    const _Float16* hchunk = hT + ((size_t)(b * (NN / 32) + ibase / 32) * CC) * 32;
    const int TP = (ichunk / 64) / 2;      // 8 staging rounds, 2 t each

    const int frow_s = tid >> 2;            // 0..63
    const int fcol_s = (tid & 3) * 16;
    const int hrow_s = tid >> 2;
    const int hcol_s = (tid & 3) * 8;

    // stage tiles t=0,1 into slot 0
#pragma unroll
    for (int th = 0; th < 2; ++th) {
        const _Float16* fsrc = fchunk + (size_t)(th * 64 + frow_s) * CC + fcol_s;
        const _Float16* hsrc = hchunk + (size_t)th * 4096 + tid * 8;
        *(half8_t*)&fbuf[0][th][frow_s][fcol_s]     = *(const half8_t*)(fsrc);
        *(half8_t*)&fbuf[0][th][frow_s][fcol_s + 8] = *(const half8_t*)(fsrc + 8);
        *(half8_t*)&hbuf[0][th][hrow_s][hcol_s]      = *(const half8_t*)(hsrc);
        *(half8_t*)&hbuf[0][th][hrow_s][32 + hcol_s] = *(const half8_t*)(hsrc + 2048);
    }
    __syncthreads();

    for (int tp = 0; tp < TP; ++tp) {
        const int buf = tp & 1;
        const bool pf = (tp + 1 < TP);
        half8_t pf0[2], pf1[2], ph0[2], ph1[2];
        if (pf) {
#pragma unroll
            for (int th = 0; th < 2; ++th) {
                const int t = (tp + 1) * 2 + th;
                const _Float16* fsrc = fchunk + (size_t)(t * 64 + frow_s) * CC + fcol_s;
                const _Float16* hsrc = hchunk + (size_t)t * 4096 + tid * 8;
                pf0[th] = *(const half8_t*)(fsrc);
                pf1[th] = *(const half8_t*)(fsrc + 8);
                ph0[th] = *(const half8_t*)(hsrc);
                ph1[th] = *(const half8_t*)(hsrc + 2048);
            }
        }

#pragma unroll
        for (int th = 0; th < 2; ++th) {
            const int t = tp * 2 + th;

            // ===== phase 1: QK for BOTH ih =====
            f32x16 s[2][2];   // [ih][jt]
#pragma unroll
            for (int ih = 0; ih < 2; ++ih) {
                f32x16 si;
#pragma unroll
                for (int rb = 0; rb < 4; ++rb) {
                    const f32x4 n4 = *(const f32x4*)&nbbuf[t * 64 + ih * 32 + rb * 8 + q5 * 4];
#pragma unroll
                    for (int k = 0; k < 4; ++k) si[rb * 4 + k] = n4[k];
                }
                s[ih][0] = si;
                s[ih][1] = si;
            }
            __builtin_amdgcn_s_setprio(1);
#pragma unroll
            for (int ih = 0; ih < 2; ++ih) {
                const _Float16* frow = &fbuf[buf][th][ih * 32 + l31][0] + q5 * 8;
#pragma unroll
                for (int kc = 0; kc < 4; ++kc) {
                    const half8_t af = *(const half8_t*)(frow + kc * 16);
                    s[ih][0] = __builtin_amdgcn_mfma_f32_32x32x16_f16(af, bg[0][kc], s[ih][0], 0, 0, 0);
                    s[ih][1] = __builtin_amdgcn_mfma_f32_32x32x16_f16(af, bg[1][kc], s[ih][1], 0, 0, 0);
                }
            }
            __builtin_amdgcn_s_setprio(0);

            // ===== phase 2: dance for BOTH ih =====
            half8_t B[2][2][2];   // [ih][jt][half]
#pragma unroll
            for (int ih = 0; ih < 2; ++ih) {
#pragma unroll
                for (int jt = 0; jt < 2; ++jt) {
                    const f32x16& sv = s[ih][jt];
                    int e[8];
#pragma unroll
                    for (int r8 = 0; r8 < 8; ++r8) {
                        e[r8] = __builtin_bit_cast(int, __builtin_amdgcn_cvt_pkrtz(
                            __builtin_exp2f(sv[r8 * 2]), __builtin_exp2f(sv[r8 * 2 + 1])));
                    }
                    int4v b0, b1;
#if __has_builtin(__builtin_amdgcn_permlane32_swap)
                    const uint2v p02 = __builtin_amdgcn_permlane32_swap(
                        (unsigned)e[0], (unsigned)e[2], false, false);
                    const uint2v p13 = __builtin_amdgcn_permlane32_swap(
                        (unsigned)e[1], (unsigned)e[3], false, false);
                    const uint2v p46 = __builtin_amdgcn_permlane32_swap(
                        (unsigned)e[4], (unsigned)e[6], false, false);
                    const uint2v p57 = __builtin_amdgcn_permlane32_swap(
                        (unsigned)e[5], (unsigned)e[7], false, false);
                    b0[0] = (int)p02[0]; b0[1] = (int)p13[0];
                    b0[2] = (int)p02[1]; b0[3] = (int)p13[1];
                    b1[0] = (int)p46[0]; b1[1] = (int)p57[0];
                    b1[2] = (int)p46[1]; b1[3] = (int)p57[1];
#else
                    const int sA = q5 ? e[0] : e[2];
                    const int sB = q5 ? e[1] : e[3];
                    const int sC = q5 ? e[4] : e[6];
                    const int sD = q5 ? e[5] : e[7];
                    const int rA = __shfl_xor(sA, 32, 64);
                    const int rB = __shfl_xor(sB, 32, 64);
                    const int rC = __shfl_xor(sC, 32, 64);
                    const int rD = __shfl_xor(sD, 32, 64);
                    b0[0] = q5 ? rA   : e[0];
                    b0[1] = q5 ? rB   : e[1];
                    b0[2] = q5 ? e[2] : rA;
                    b0[3] = q5 ? e[3] : rB;
                    b1[0] = q5 ? rC   : e[4];
                    b1[1] = q5 ? rD   : e[5];
                    b1[2] = q5 ? e[6] : rC;
                    b1[3] = q5 ? e[7] : rD;
#endif
                    B[ih][jt][0] = __builtin_bit_cast(half8_t, b0);
                    B[ih][jt][1] = __builtin_bit_cast(half8_t, b1);
                }
            }

            // ===== phase 3: PV for BOTH ih =====
            __builtin_amdgcn_s_setprio(1);
#pragma unroll
            for (int ih = 0; ih < 2; ++ih) {
#pragma unroll
                for (int ct = 0; ct < 2; ++ct) {
                    const half8_t ah0 = *(const half8_t*)(&hbuf[buf][th][ct * 32 + l31][0] + ih * 32 + q5 * 8);
                    const half8_t ah1 = *(const half8_t*)(&hbuf[buf][th][ct * 32 + l31][0] + ih * 32 + 16 + q5 * 8);
                    acc[0][ct] = __builtin_amdgcn_mfma_f32_32x32x16_f16(ah0, B[ih][0][0], acc[0][ct], 0, 0, 0);
                    acc[0][ct] = __builtin_amdgcn_mfma_f32_32x32x16_f16(ah1, B[ih][0][1], acc[0][ct], 0, 0, 0);
                    acc[1][ct] = __builtin_amdgcn_mfma_f32_32x32x16_f16(ah0, B[ih][1][0], acc[1][ct], 0, 0, 0);
                    acc[1][ct] = __builtin_amdgcn_mfma_f32_32x32x16_f16(ah1, B[ih][1][1], acc[1][ct], 0, 0, 0);
                }
            }
            __builtin_amdgcn_s_setprio(0);
        }

        if (pf) {
#pragma unroll
            for (int th = 0; th < 2; ++th) {
                *(half8_t*)&fbuf[buf ^ 1][th][frow_s][fcol_s]     = pf0[th];
                *(half8_t*)&fbuf[buf ^ 1][th][frow_s][fcol_s + 8] = pf1[th];
                *(half8_t*)&hbuf[buf ^ 1][th][hrow_s][hcol_s]      = ph0[th];
                *(half8_t*)&hbuf[buf ^ 1][th][hrow_s][32 + hcol_s] = ph1[th];
            }
        }
        __syncthreads();
    }

    _Float16* pb_out = pout + (((size_t)ic * BB + b) * CC) * NN;
#pragma unroll
    for (int jt = 0; jt < 2; ++jt) {
        const int j = jbase + jt * 32 + l31;
#pragma unroll
        for (int ct = 0; ct < 2; ++ct) {
#pragma unroll
            for (int r = 0; r < 16; ++r) {
                const int c = ct * 32 + (r & 3) + 8 * (r >> 2) + 4 * q5;
                pb_out[(size_t)c * NN + j] = (_Float16)acc[jt][ct][r];
            }
        }
    }

    // ---- fused combine: last ic-block for (b, jbx) does the reduction ----
    __threadfence();                       // release pout writes (device scope)
    if (tid == 0) {
        done_cnt = __hip_atomic_fetch_add(cnt + (b * 16 + blockIdx.x), 1u,
                       __ATOMIC_ACQ_REL, __HIP_MEMORY_SCOPE_AGENT);
    }
    __syncthreads();
    if (done_cnt == (unsigned)(NICT - 1)) {
        __threadfence();                   // acquire: see other blocks' pout
        const float gam = gammap[0];
        const size_t TOT = (size_t)BB * CC * NN;
        const int jb0 = blockIdx.x * 256;
#pragma unroll
        for (int it = 0; it < 8; ++it) {
            const int idx = it * 256 + tid;       // 2048 vec8-chunks (64c x 32)
            const int c   = idx >> 5;
            const int j8  = (idx & 31) * 8;
            const size_t off = ((size_t)b * CC + c) * NN + jb0 + j8;
            float sacc[8] = {0.f, 0.f, 0.f, 0.f, 0.f, 0.f, 0.f, 0.f};
#pragma unroll
            for (int icc = 0; icc < NICT; ++icc) {   // same order as old combine
                const half8_t p = *(const half8_t*)(pout + (size_t)icc * TOT + off);
#pragma unroll
                for (int k = 0; k < 8; ++k) sacc[k] += (float)p[k];
            }
            const f32x4 x0 = *(const f32x4*)(xres + off);
            const f32x4 x1 = *(const f32x4*)(xres + off + 4);
            f32x4 o0, o1;
#pragma unroll
            for (int k = 0; k < 4; ++k) {
                o0[k] = gam * sacc[k] + x0[k];
                o1[k] = gam * sacc[k + 4] + x1[k];
            }
            *(f32x4*)(outp + off) = o0;
            *(f32x4*)(outp + off + 4) = o1;
        }
    }
}

// ---------------------------------------------------------------------------
extern "C" void kernel_launch(void* const* d_in, const int* in_sizes, int n_in,
                              void* d_out, int out_size, void* d_ws, size_t ws_size,
                              hipStream_t stream) {
    const float* x     = (const float*)d_in[0];
    const float* Wf    = (const float*)d_in[1];
    const float* bf    = (const float*)d_in[2];
    const float* Wg    = (const float*)d_in[3];
    const float* bg    = (const float*)d_in[4];
    const float* Wh    = (const float*)d_in[5];
    const float* bh    = (const float*)d_in[6];
    const float* gamma = (const float*)d_in[7];
    float* out = (float*)d_out;

    const size_t TOT = (size_t)BB * CC * NN;        // 2M elems
    _Float16* fT   = (_Float16*)d_ws;               // 4 MB
    _Float16* gT   = fT + TOT;                      // 4 MB
    _Float16* hT   = gT + TOT;                      // 4 MB
    _Float16* pout = hT + TOT;                      // 4 * 4 MB
    float* lpart   = (float*)(pout + (size_t)4 * TOT);  // 1 MB
    unsigned* cnt  = (unsigned*)(lpart + (size_t)JCH * BB * NN);  // 512 B

    hipMemsetAsync(cnt, 0, 16 * BB * sizeof(unsigned), stream);
    qkv_kernel<<<dim3(NN / 32, BB), 384, 0, stream>>>(
        x, Wf, bf, Wg, bg, Wh, bh, fT, gT, hT);
    stats_kernel<<<dim3(NN / 128, BB, JCH), 256, 0, stream>>>(fT, gT, lpart);
    attn_kernel<4><<<dim3(NN / 256, BB, 4), 256, 0, stream>>>(
        fT, gT, hT, lpart, pout, x, gamma, out, cnt);
}

// Round 13
// 167.022 us; speedup vs baseline: 1.5204x; 1.5204x over previous
//
#include <hip/hip_runtime.h>

#define BB 8
#define CC 64
#define NN 4096
#define JCH 4            // j-chunks in stats pass (R13: 8->4, halves stats blocks)
#define LOG2E 1.4426950408889634f

typedef float f32x4  __attribute__((ext_vector_type(4)));
typedef float f32x16 __attribute__((ext_vector_type(16)));
typedef _Float16 half8_t __attribute__((ext_vector_type(8)));
typedef int int4v __attribute__((ext_vector_type(4)));
typedef unsigned uint2v __attribute__((ext_vector_type(2)));

// 32x32x16 f16 MFMA layouts (gfx950):
//   A[m][k]: m = lane&31, k = (lane>>5)*8 + idx   (8 halves)
//   B[k][n]: n = lane&31, k = (lane>>5)*8 + idx
//   C/D:     col = lane&31, row = (reg&3) + 8*(reg>>2) + 4*(lane>>5)
//
// SESSION LEDGER:
//   attn pinned ~57us across 8 structural variants (2 waves/SIMD grid-capped,
//   VALU 52% + MFMA 23% on separate pipes, neither saturable).
//   stats launch_bounds: (256,4) ONLY non-spilling config (R9/R10: 8 and 6
//   both cliff to 32-40 VGPR + 400-490MB scratch on the unified RF).
//   R12: fusing combine via device-scope ACQ_REL atomics POISONED attn
//   (57->145us): agent-scope acquire invalidates per-XCD L2 in all 512
//   blocks -> peers' L2-resident f/g/h reads become HBM misses. Do not put
//   agent-scope fences/atomics in hot multi-block kernels.
//   R12 budget: combine + its launch gap ~ 3us; non-attn ~110us is stats
//   (~37) + qkv (~10) + fixed harness overhead. Launch-count reduction is
//   not a lever here.

// ---------------------------------------------------------------------------
// Kernel A: fused 1x1-conv QKV via MFMA. grid (NN/32, B), block 384 (6 waves).
// ---------------------------------------------------------------------------
__global__ __launch_bounds__(384, 6) void qkv_kernel(
    const float* __restrict__ x,
    const float* __restrict__ Wf, const float* __restrict__ bf,
    const float* __restrict__ Wg, const float* __restrict__ bg,
    const float* __restrict__ Wh, const float* __restrict__ bh,
    _Float16* __restrict__ fT, _Float16* __restrict__ gT,
    _Float16* __restrict__ hT)
{
    __shared__ float xbuf[64][36];         // 9.2 KB, stride 36 floats

    const int tid  = threadIdx.x;
    const int lane = tid & 63;
    const int wv   = tid >> 6;             // 0..5
    const int l31  = lane & 31;
    const int q5   = lane >> 5;
    const int z    = wv >> 1;              // 0=f 1=g 2=h
    const int ot   = wv & 1;               // o-tile
    const int n0   = blockIdx.x * 32;
    const int b    = blockIdx.y;

    if (tid < 256) {
        const int row = tid >> 2;
        const int px4 = (tid & 3) * 8;
        const float* src = x + (size_t)(b * CC + row) * NN + n0 + px4;
        *(f32x4*)&xbuf[row][px4]     = *(const f32x4*)(src);
        *(f32x4*)&xbuf[row][px4 + 4] = *(const f32x4*)(src + 4);
    }
    __syncthreads();

    half8_t xf[4];
#pragma unroll
    for (int kc = 0; kc < 4; ++kc) {
        const int kb = kc * 16 + q5 * 8;
        int4v p;
#pragma unroll
        for (int h2 = 0; h2 < 4; ++h2) {
            p[h2] = __builtin_bit_cast(int, __builtin_amdgcn_cvt_pkrtz(
                xbuf[kb + h2 * 2][l31], xbuf[kb + h2 * 2 + 1][l31]));
        }
        xf[kc] = __builtin_bit_cast(half8_t, p);
    }

    const float* W    = (z == 0) ? Wf : ((z == 1) ? Wg : Wh);
    const float* bias = (z == 0) ? bf : ((z == 1) ? bg : bh);

    half8_t wf[4];
    {
        const float* wrow = W + (size_t)(ot * 32 + l31) * CC;
#pragma unroll
        for (int kc = 0; kc < 4; ++kc) {
            const f32x4 w0 = *(const f32x4*)(wrow + kc * 16 + q5 * 8);
            const f32x4 w1 = *(const f32x4*)(wrow + kc * 16 + q5 * 8 + 4);
            int4v p;
            p[0] = __builtin_bit_cast(int, __builtin_amdgcn_cvt_pkrtz(w0[0], w0[1]));
            p[1] = __builtin_bit_cast(int, __builtin_amdgcn_cvt_pkrtz(w0[2], w0[3]));
            p[2] = __builtin_bit_cast(int, __builtin_amdgcn_cvt_pkrtz(w1[0], w1[1]));
            p[3] = __builtin_bit_cast(int, __builtin_amdgcn_cvt_pkrtz(w1[2], w1[3]));
            wf[kc] = __builtin_bit_cast(half8_t, p);
        }
    }

    if (z < 2) {
        f32x16 acc = {};
#pragma unroll
        for (int kc = 0; kc < 4; ++kc)
            acc = __builtin_amdgcn_mfma_f32_32x32x16_f16(xf[kc], wf[kc], acc, 0, 0, 0);
        _Float16* dstT = (z == 0) ? fT : gT;
        const float scale = (z == 0) ? LOG2E : 1.0f;
        const float bv = bias[ot * 32 + l31];
#pragma unroll
        for (int r = 0; r < 16; ++r) {
            const int prow = (r & 3) + 8 * (r >> 2) + 4 * q5;
            dstT[(size_t)(b * NN + n0 + prow) * CC + ot * 32 + l31] =
                (_Float16)((acc[r] + bv) * scale);
        }
    } else {
        f32x16 acc = {};
#pragma unroll
        for (int kc = 0; kc < 4; ++kc)
            acc = __builtin_amdgcn_mfma_f32_32x32x16_f16(wf[kc], xf[kc], acc, 0, 0, 0);
        _Float16* hbase = hT + ((size_t)(b * (NN / 32) + blockIdx.x) * CC) * 32;
#pragma unroll
        for (int rb = 0; rb < 4; ++rb) {
            const f32x4 b4 = *(const f32x4*)(bias + ot * 32 + rb * 8 + q5 * 4);
#pragma unroll
            for (int k = 0; k < 4; ++k) {
                const int c = ot * 32 + rb * 8 + q5 * 4 + k;
                hbase[(size_t)c * 32 + l31] = (_Float16)(acc[rb * 4 + k] + b4[k]);
            }
        }
    }
}

// ---------------------------------------------------------------------------
// Kernel B: partial row sums of exp2(logits). grid (NN/128, B, JCH), block 256.
// launch_bounds (256,4): the ONLY verified non-spilling config (R9/R10).
// R13: JCH=4 -> 1024 blocks (exactly the 4/CU residency bound), T=16/block:
// prologue (a-loads, tile-0 stage) + epilogue (shuffle-reduce) amortize 2x,
// and block scheduling rounds drop 2 -> 1. Register footprint unchanged.
// ---------------------------------------------------------------------------
__global__ __launch_bounds__(256, 4) void stats_kernel(
    const _Float16* __restrict__ fT, const _Float16* __restrict__ gT,
    float* __restrict__ lpart)
{
    __shared__ _Float16 gbuf[2][64][72];   // stride 72 halves

    const int lane = threadIdx.x & 63;
    const int wv   = threadIdx.x >> 6;
    const int b    = blockIdx.y;
    const int jc   = blockIdx.z;
    const int i0   = blockIdx.x * 128 + wv * 32;
    const int l31  = lane & 31;
    const int q5   = lane >> 5;

    half8_t a[4];
    const _Float16* fa = fT + (size_t)(b * NN + i0 + l31) * CC + q5 * 8;
#pragma unroll
    for (int kc = 0; kc < 4; ++kc) a[kc] = *(const half8_t*)(fa + kc * 16);

    const _Float16* gchunk = gT + (size_t)(b * NN + jc * (NN / JCH)) * CC;
    const int T = NN / JCH / 64;   // 16 tiles of 64 j

    const int srow = wv * 16 + (lane >> 3);
    const int scol = (lane & 7) * 8;

    {   // stage tile 0
        const half8_t v0 = *(const half8_t*)(gchunk + (size_t)srow * CC + scol);
        const half8_t v1 = *(const half8_t*)(gchunk + (size_t)(srow + 8) * CC + scol);
        *(half8_t*)&gbuf[0][srow][scol] = v0;
        *(half8_t*)&gbuf[0][srow + 8][scol] = v1;
    }
    __syncthreads();

    float l16[16];
#pragma unroll
    for (int r = 0; r < 16; ++r) l16[r] = 0.f;

    for (int t = 0; t < T; ++t) {
        const int buf = t & 1;
        const bool pf = (t + 1 < T);
        half8_t p0, p1;
        if (pf) {
            const _Float16* src = gchunk + (size_t)((t + 1) * 64 + srow) * CC + scol;
            p0 = *(const half8_t*)(src);
            p1 = *(const half8_t*)(src + 8 * CC);
        }
#pragma unroll
        for (int js = 0; js < 2; ++js) {
            const _Float16* grow = &gbuf[buf][js * 32 + l31][0] + q5 * 8;
            f32x16 s = {};
#pragma unroll
            for (int kc = 0; kc < 4; ++kc) {
                const half8_t bfr = *(const half8_t*)(grow + kc * 16);
                s = __builtin_amdgcn_mfma_f32_32x32x16_f16(a[kc], bfr, s, 0, 0, 0);
            }
#pragma unroll
            for (int r = 0; r < 16; ++r) l16[r] += __builtin_exp2f(s[r]);
        }
        if (pf) {
            *(half8_t*)&gbuf[buf ^ 1][srow][scol] = p0;
            *(half8_t*)&gbuf[buf ^ 1][srow + 8][scol] = p1;
        }
        __syncthreads();
    }

#pragma unroll
    for (int r = 0; r < 16; ++r) {
#pragma unroll
        for (int off = 1; off < 32; off <<= 1)
            l16[r] += __shfl_xor(l16[r], off);
    }

    if (l31 == 0) {
        float* lp = lpart + (size_t)jc * BB * NN + b * NN + i0;
#pragma unroll
        for (int rb = 0; rb < 4; ++rb) {
            f32x4 v;
#pragma unroll
            for (int k = 0; k < 4; ++k) v[k] = l16[rb * 4 + k];
            *(f32x4*)(lp + rb * 8 + q5 * 4) = v;
        }
    }
}

// ---------------------------------------------------------------------------
// Kernel C: partial out chunks. grid (NN/256, B, NICT=4), block 256.
// R8 structure (2-deep staging, 8 barriers, setprio, permlane dance) —
// best measured attn at 57.5us; pinned across 8 structural variants.
// ---------------------------------------------------------------------------
template <int NICT>
__global__ __launch_bounds__(256, 2) void attn_kernel(
    const _Float16* __restrict__ fT, const _Float16* __restrict__ gT,
    const _Float16* __restrict__ hT, const float* __restrict__ lpart,
    _Float16* __restrict__ pout)
{
    constexpr int ichunk = NN / NICT;      // 1024
    __shared__ _Float16 fbuf[2][2][64][72];   // 36.9 KB
    __shared__ _Float16 hbuf[2][2][64][72];   // 36.9 KB
    __shared__ float nbbuf[ichunk];           // 4 KB

    const int lane = threadIdx.x & 63;
    const int wv   = threadIdx.x >> 6;
    const int b    = blockIdx.y;
    const int ic   = blockIdx.z;
    const int l31  = lane & 31;
    const int q5   = lane >> 5;
    const int jbase = blockIdx.x * 256 + wv * 64;

    const int ibase  = ic * ichunk;
    const int tid    = threadIdx.x;

    // ---- fused rmerge: nbias for this i-chunk (identical jc-sum order) ----
    if (tid * 4 < ichunk) {
        const float* lp0 = lpart + b * NN + ibase + tid * 4;
        f32x4 sum = *(const f32x4*)(lp0);
#pragma unroll
        for (int jc = 1; jc < JCH; ++jc) {
            const f32x4 v = *(const f32x4*)(lp0 + (size_t)jc * BB * NN);
#pragma unroll
            for (int k = 0; k < 4; ++k) sum[k] += v[k];
        }
        f32x4 nb4;
#pragma unroll
        for (int k = 0; k < 4; ++k) nb4[k] = -__builtin_log2f(sum[k]);
        *(f32x4*)&nbbuf[tid * 4] = nb4;
    }

    half8_t bg[2][4];
#pragma unroll
    for (int jt = 0; jt < 2; ++jt) {
        const _Float16* grow = gT + (size_t)(b * NN + jbase + jt * 32 + l31) * CC + q5 * 8;
#pragma unroll
        for (int kc = 0; kc < 4; ++kc) bg[jt][kc] = *(const half8_t*)(grow + kc * 16);
    }

    f32x16 acc[2][2] = {};   // [jt][ct]

    const _Float16* fchunk = fT + ((size_t)b * NN + ibase) * CC;
    const _Float16* hchunk = hT + ((size_t)(b * (NN / 32) + ibase / 32) * CC) * 32;
    const int TP = (ichunk / 64) / 2;      // 8 staging rounds, 2 t each

    const int frow_s = tid >> 2;            // 0..63
    const int fcol_s = (tid & 3) * 16;
    const int hrow_s = tid >> 2;
    const int hcol_s = (tid & 3) * 8;

    // stage tiles t=0,1 into slot 0
#pragma unroll
    for (int th = 0; th < 2; ++th) {
        const _Float16* fsrc = fchunk + (size_t)(th * 64 + frow_s) * CC + fcol_s;
        const _Float16* hsrc = hchunk + (size_t)th * 4096 + tid * 8;
        *(half8_t*)&fbuf[0][th][frow_s][fcol_s]     = *(const half8_t*)(fsrc);
        *(half8_t*)&fbuf[0][th][frow_s][fcol_s + 8] = *(const half8_t*)(fsrc + 8);
        *(half8_t*)&hbuf[0][th][hrow_s][hcol_s]      = *(const half8_t*)(hsrc);
        *(half8_t*)&hbuf[0][th][hrow_s][32 + hcol_s] = *(const half8_t*)(hsrc + 2048);
    }
    __syncthreads();

    for (int tp = 0; tp < TP; ++tp) {
        const int buf = tp & 1;
        const bool pf = (tp + 1 < TP);
        half8_t pf0[2], pf1[2], ph0[2], ph1[2];
        if (pf) {
#pragma unroll
            for (int th = 0; th < 2; ++th) {
                const int t = (tp + 1) * 2 + th;
                const _Float16* fsrc = fchunk + (size_t)(t * 64 + frow_s) * CC + fcol_s;
                const _Float16* hsrc = hchunk + (size_t)t * 4096 + tid * 8;
                pf0[th] = *(const half8_t*)(fsrc);
                pf1[th] = *(const half8_t*)(fsrc + 8);
                ph0[th] = *(const half8_t*)(hsrc);
                ph1[th] = *(const half8_t*)(hsrc + 2048);
            }
        }

#pragma unroll
        for (int th = 0; th < 2; ++th) {
            const int t = tp * 2 + th;

            // ===== phase 1: QK for BOTH ih =====
            f32x16 s[2][2];   // [ih][jt]
#pragma unroll
            for (int ih = 0; ih < 2; ++ih) {
                f32x16 si;
#pragma unroll
                for (int rb = 0; rb < 4; ++rb) {
                    const f32x4 n4 = *(const f32x4*)&nbbuf[t * 64 + ih * 32 + rb * 8 + q5 * 4];
#pragma unroll
                    for (int k = 0; k < 4; ++k) si[rb * 4 + k] = n4[k];
                }
                s[ih][0] = si;
                s[ih][1] = si;
            }
            __builtin_amdgcn_s_setprio(1);
#pragma unroll
            for (int ih = 0; ih < 2; ++ih) {
                const _Float16* frow = &fbuf[buf][th][ih * 32 + l31][0] + q5 * 8;
#pragma unroll
                for (int kc = 0; kc < 4; ++kc) {
                    const half8_t af = *(const half8_t*)(frow + kc * 16);
                    s[ih][0] = __builtin_amdgcn_mfma_f32_32x32x16_f16(af, bg[0][kc], s[ih][0], 0, 0, 0);
                    s[ih][1] = __builtin_amdgcn_mfma_f32_32x32x16_f16(af, bg[1][kc], s[ih][1], 0, 0, 0);
                }
            }
            __builtin_amdgcn_s_setprio(0);

            // ===== phase 2: dance for BOTH ih =====
            half8_t B[2][2][2];   // [ih][jt][half]
#pragma unroll
            for (int ih = 0; ih < 2; ++ih) {
#pragma unroll
                for (int jt = 0; jt < 2; ++jt) {
                    const f32x16& sv = s[ih][jt];
                    int e[8];
#pragma unroll
                    for (int r8 = 0; r8 < 8; ++r8) {
                        e[r8] = __builtin_bit_cast(int, __builtin_amdgcn_cvt_pkrtz(
                            __builtin_exp2f(sv[r8 * 2]), __builtin_exp2f(sv[r8 * 2 + 1])));
                    }
                    int4v b0, b1;
#if __has_builtin(__builtin_amdgcn_permlane32_swap)
                    const uint2v p02 = __builtin_amdgcn_permlane32_swap(
                        (unsigned)e[0], (unsigned)e[2], false, false);
                    const uint2v p13 = __builtin_amdgcn_permlane32_swap(
                        (unsigned)e[1], (unsigned)e[3], false, false);
                    const uint2v p46 = __builtin_amdgcn_permlane32_swap(
                        (unsigned)e[4], (unsigned)e[6], false, false);
                    const uint2v p57 = __builtin_amdgcn_permlane32_swap(
                        (unsigned)e[5], (unsigned)e[7], false, false);
                    b0[0] = (int)p02[0]; b0[1] = (int)p13[0];
                    b0[2] = (int)p02[1]; b0[3] = (int)p13[1];
                    b1[0] = (int)p46[0]; b1[1] = (int)p57[0];
                    b1[2] = (int)p46[1]; b1[3] = (int)p57[1];
#else
                    const int sA = q5 ? e[0] : e[2];
                    const int sB = q5 ? e[1] : e[3];
                    const int sC = q5 ? e[4] : e[6];
                    const int sD = q5 ? e[5] : e[7];
                    const int rA = __shfl_xor(sA, 32, 64);
                    const int rB = __shfl_xor(sB, 32, 64);
                    const int rC = __shfl_xor(sC, 32, 64);
                    const int rD = __shfl_xor(sD, 32, 64);
                    b0[0] = q5 ? rA   : e[0];
                    b0[1] = q5 ? rB   : e[1];
                    b0[2] = q5 ? e[2] : rA;
                    b0[3] = q5 ? e[3] : rB;
                    b1[0] = q5 ? rC   : e[4];
                    b1[1] = q5 ? rD   : e[5];
                    b1[2] = q5 ? e[6] : rC;
                    b1[3] = q5 ? e[7] : rD;
#endif
                    B[ih][jt][0] = __builtin_bit_cast(half8_t, b0);
                    B[ih][jt][1] = __builtin_bit_cast(half8_t, b1);
                }
            }

            // ===== phase 3: PV for BOTH ih =====
            __builtin_amdgcn_s_setprio(1);
#pragma unroll
            for (int ih = 0; ih < 2; ++ih) {
#pragma unroll
                for (int ct = 0; ct < 2; ++ct) {
                    const half8_t ah0 = *(const half8_t*)(&hbuf[buf][th][ct * 32 + l31][0] + ih * 32 + q5 * 8);
                    const half8_t ah1 = *(const half8_t*)(&hbuf[buf][th][ct * 32 + l31][0] + ih * 32 + 16 + q5 * 8);
                    acc[0][ct] = __builtin_amdgcn_mfma_f32_32x32x16_f16(ah0, B[ih][0][0], acc[0][ct], 0, 0, 0);
                    acc[0][ct] = __builtin_amdgcn_mfma_f32_32x32x16_f16(ah1, B[ih][0][1], acc[0][ct], 0, 0, 0);
                    acc[1][ct] = __builtin_amdgcn_mfma_f32_32x32x16_f16(ah0, B[ih][1][0], acc[1][ct], 0, 0, 0);
                    acc[1][ct] = __builtin_amdgcn_mfma_f32_32x32x16_f16(ah1, B[ih][1][1], acc[1][ct], 0, 0, 0);
                }
            }
            __builtin_amdgcn_s_setprio(0);
        }

        if (pf) {
#pragma unroll
            for (int th = 0; th < 2; ++th) {
                *(half8_t*)&fbuf[buf ^ 1][th][frow_s][fcol_s]     = pf0[th];
                *(half8_t*)&fbuf[buf ^ 1][th][frow_s][fcol_s + 8] = pf1[th];
                *(half8_t*)&hbuf[buf ^ 1][th][hrow_s][hcol_s]      = ph0[th];
                *(half8_t*)&hbuf[buf ^ 1][th][hrow_s][32 + hcol_s] = ph1[th];
            }
        }
        __syncthreads();
    }

    _Float16* pb_out = pout + (((size_t)ic * BB + b) * CC) * NN;
#pragma unroll
    for (int jt = 0; jt < 2; ++jt) {
        const int j = jbase + jt * 32 + l31;
#pragma unroll
        for (int ct = 0; ct < 2; ++ct) {
#pragma unroll
            for (int r = 0; r < 16; ++r) {
                const int c = ct * 32 + (r & 3) + 8 * (r >> 2) + 4 * q5;
                pb_out[(size_t)c * NN + j] = (_Float16)acc[jt][ct][r];
            }
        }
    }
}

// ---------------------------------------------------------------------------
// Kernel D: out = gamma * sum_ic pout[ic] + x.
// ---------------------------------------------------------------------------
template <int NICT>
__global__ __launch_bounds__(256) void combine_kernel(
    const float* __restrict__ x, const float* __restrict__ gammap,
    const _Float16* __restrict__ pout, float* __restrict__ out)
{
    const float gam = gammap[0];
    const size_t i8 = ((size_t)blockIdx.x * 256 + threadIdx.x) * 8;
    const size_t TOT = (size_t)BB * CC * NN;

    float s[8] = {0.f, 0.f, 0.f, 0.f, 0.f, 0.f, 0.f, 0.f};
#pragma unroll
    for (int ic = 0; ic < NICT; ++ic) {
        const half8_t p = *(const half8_t*)(pout + ic * TOT + i8);
#pragma unroll
        for (int k = 0; k < 8; ++k) s[k] += (float)p[k];
    }
    const f32x4 x0 = *(const f32x4*)(x + i8);
    const f32x4 x1 = *(const f32x4*)(x + i8 + 4);
    f32x4 o0, o1;
#pragma unroll
    for (int k = 0; k < 4; ++k) { o0[k] = gam * s[k] + x0[k]; o1[k] = gam * s[k + 4] + x1[k]; }
    *(f32x4*)(out + i8) = o0;
    *(f32x4*)(out + i8 + 4) = o1;
}

// ---------------------------------------------------------------------------
extern "C" void kernel_launch(void* const* d_in, const int* in_sizes, int n_in,
                              void* d_out, int out_size, void* d_ws, size_t ws_size,
                              hipStream_t stream) {
    const float* x     = (const float*)d_in[0];
    const float* Wf    = (const float*)d_in[1];
    const float* bf    = (const float*)d_in[2];
    const float* Wg    = (const float*)d_in[3];
    const float* bg    = (const float*)d_in[4];
    const float* Wh    = (const float*)d_in[5];
    const float* bh    = (const float*)d_in[6];
    const float* gamma = (const float*)d_in[7];
    float* out = (float*)d_out;

    const size_t TOT = (size_t)BB * CC * NN;        // 2M elems
    _Float16* fT   = (_Float16*)d_ws;               // 4 MB
    _Float16* gT   = fT + TOT;                      // 4 MB
    _Float16* hT   = gT + TOT;                      // 4 MB
    _Float16* pout = hT + TOT;                      // 4 * 4 MB
    float* lpart   = (float*)(pout + (size_t)4 * TOT);  // 0.5 MB (JCH=4)

    qkv_kernel<<<dim3(NN / 32, BB), 384, 0, stream>>>(
        x, Wf, bf, Wg, bg, Wh, bh, fT, gT, hT);
    stats_kernel<<<dim3(NN / 128, BB, JCH), 256, 0, stream>>>(fT, gT, lpart);
    attn_kernel<4><<<dim3(NN / 256, BB, 4), 256, 0, stream>>>(fT, gT, hT, lpart, pout);
    combine_kernel<4><<<dim3(TOT / (256 * 8)), 256, 0, stream>>>(x, gamma, pout, out);
}